// Round 3
// baseline (4699.085 us; speedup 1.0000x reference)
//
#include <hip/hip_runtime.h>
#include <cstdint>
#include <cstddef>

#define B_   2
#define N_   8192
#define M_   2048
#define K_   32
#define C0_  64
#define C1_  128
#define C2_  256
#define CIN_ 67

// Exact-match distance: reference computes sum((a-b)**2, axis=-1) in f32 as
// ((dx^2 + dy^2) + dz^2) with no FMA contraction. _rn intrinsics forbid
// contract-fast fma fusion (would flip argmax / radius-boundary decisions).
__device__ __forceinline__ float sqdist_rn(float ax, float ay, float az,
                                           float bx, float by, float bz) {
  float dx = __fsub_rn(ax, bx);
  float dy = __fsub_rn(ay, by);
  float dz = __fsub_rn(az, bz);
  return __fadd_rn(__fadd_rn(__fmul_rn(dx, dx), __fmul_rn(dy, dy)),
                   __fmul_rn(dz, dz));
}

__device__ __forceinline__ int morton8(int ix, int iy, int iz) {
  int m = 0;
#pragma unroll
  for (int b = 0; b < 3; ++b) {
    m |= (((ix >> b) & 1) << (3 * b + 2)) | (((iy >> b) & 1) << (3 * b + 1)) |
         (((iz >> b) & 1) << (3 * b + 0));
  }
  return m;
}

// ---------------------------------------------------------------------------
// 1) Furthest point sampling with exact spatial pruning.
//    One block (1024 thr, 16 waves) per batch.
//    Setup: counting-sort points by 8^3 Morton cell (LDS). Thread t owns the
//    8 sorted points [8t, 8t+8) in registers + bounding sphere (c, r).
//    Scatter order is atomic-nondeterministic but OUTPUT-invariant: updates
//    are exact min() ops (order-free), skips provably change nothing, and
//    argmax ties break on the ORIGINAL index carried as payload.
//    Per iteration:
//      a) skip test: (|last-c| - r)^2 > maxd*(1+1e-4) -> bucket provably
//         unaffected (conservative margin >> fp slop; d[] stays bit-exact).
//      b) dirty threads re-run the exact 8-pt update + candidate rebuild.
//      c) dirty WAVES redo the 6-step shfl butterfly (d, idx, x, y, z) and
//         refresh their LDS slot; clean waves keep the cached slot (valid:
//         their maxd is unchanged; the winning wave is always dirty).
//      d) barrier; wave 0 lanes 0..15 reduce the 16 slots (4-step shfl);
//         lane 0 publishes winner coords + writes new_xyz; barrier.
//    Tie-break everywhere: (d greater) or (d equal and orig idx smaller)
//    == jnp.argmax first-occurrence.
// ---------------------------------------------------------------------------
__global__ __launch_bounds__(1024, 1) void fps_kernel(const float* __restrict__ xyz,
                                                      float* __restrict__ new_xyz) {
  const int b = blockIdx.x;
  const int t = threadIdx.x;
  const int lane = t & 63;
  const int w = t >> 6;
  const float* xb = xyz + (size_t)b * N_ * 3;

  __shared__ float sx[N_], sy[N_], sz[N_];
  __shared__ int sid[N_];
  __shared__ int hist[512];
  __shared__ int boff[512];
  __shared__ int wsum[8];
  __shared__ float slotD[16], slotX[16], slotY[16], slotZ[16];
  __shared__ int slotI[16];
  __shared__ float fXYZ[3];

  // ---- counting sort by morton cell ----
  if (t < 512) hist[t] = 0;
  __syncthreads();
#pragma unroll
  for (int rr = 0; rr < 8; ++rr) {
    int i = rr * 1024 + t;
    float X = xb[i * 3 + 0], Y = xb[i * 3 + 1], Z = xb[i * 3 + 2];
    int ix = min(7, max(0, (int)(X * 8.0f)));
    int iy = min(7, max(0, (int)(Y * 8.0f)));
    int iz = min(7, max(0, (int)(Z * 8.0f)));
    atomicAdd(&hist[morton8(ix, iy, iz)], 1);
  }
  __syncthreads();
  // exclusive scan of 512 bins (8 active waves)
  {
    int ov = (t < 512) ? hist[t] : 0;
    int v = ov;
#pragma unroll
    for (int off = 1; off < 64; off <<= 1) {
      int n = __shfl_up(v, off);
      if (lane >= off) v += n;
    }
    if (t < 512 && lane == 63) wsum[w] = v;
    __syncthreads();
    if (t == 0) {
      int acc = 0;
#pragma unroll
      for (int j = 0; j < 8; ++j) { int x0 = wsum[j]; wsum[j] = acc; acc += x0; }
    }
    __syncthreads();
    if (t < 512) boff[t] = v - ov + wsum[w];
  }
  __syncthreads();
#pragma unroll
  for (int rr = 0; rr < 8; ++rr) {
    int i = rr * 1024 + t;
    float X = xb[i * 3 + 0], Y = xb[i * 3 + 1], Z = xb[i * 3 + 2];
    int ix = min(7, max(0, (int)(X * 8.0f)));
    int iy = min(7, max(0, (int)(Y * 8.0f)));
    int iz = min(7, max(0, (int)(Z * 8.0f)));
    int pos = atomicAdd(&boff[morton8(ix, iy, iz)], 1);
    sx[pos] = X; sy[pos] = Y; sz[pos] = Z; sid[pos] = i;
  }
  __syncthreads();

  // ---- per-thread bucket: 8 points into registers + bounding sphere ----
  float px[8], py[8], pz[8], d[8];
  int pid[8];
#pragma unroll
  for (int k = 0; k < 8; ++k) {
    int p = 8 * t + k;
    px[k] = sx[p]; py[k] = sy[p]; pz[k] = sz[p]; pid[k] = sid[p];
    d[k] = 1e10f;  // == f32(10000000000.0), matches jnp init exactly
  }
  float cx = 0.f, cy = 0.f, cz = 0.f;
#pragma unroll
  for (int k = 0; k < 8; ++k) { cx += px[k]; cy += py[k]; cz += pz[k]; }
  cx *= 0.125f; cy *= 0.125f; cz *= 0.125f;
  float r2m = 0.f;
#pragma unroll
  for (int k = 0; k < 8; ++k) {
    float dx = px[k] - cx, dy = py[k] - cy, dz = pz[k] - cz;
    r2m = fmaxf(r2m, dx * dx + dy * dy + dz * dz);
  }
  const float rad = sqrtf(r2m) * 1.00002f + 1e-12f;

  // cached per-thread candidate (valid whenever bucket unchanged).
  // bd == exact max of d[] over bucket; iter 1 never skips (bd=1e10 huge).
  float bd = 1e10f, bx = px[0], by = py[0], bz = pz[0];
  int bi = pid[0];

  // first selected index = 0 (original order)
  float lx = xb[0], ly = xb[1], lz = xb[2];
  if (t == 0) {
    new_xyz[(size_t)b * M_ * 3 + 0] = lx;
    new_xyz[(size_t)b * M_ * 3 + 1] = ly;
    new_xyz[(size_t)b * M_ * 3 + 2] = lz;
  }

  for (int it = 1; it < M_; ++it) {
    // ---- conservative skip test (pruning-quality precision only) ----
    float ex = lx - cx, ey = ly - cy, ez = lz - cz;
    float dc2 = ex * ex + ey * ey + ez * ez;
    float s = sqrtf(dc2) - rad;
    bool skip = (s > 0.f) && (s * s > bd * 1.0001f);
    if (!skip) {
      float nbd = -1.f; int nbi = 0; float nx = 0.f, ny = 0.f, nz = 0.f;
#pragma unroll
      for (int k = 0; k < 8; ++k) {
        float dist = sqdist_rn(px[k], py[k], pz[k], lx, ly, lz);
        float dm = fminf(d[k], dist);
        d[k] = dm;
        bool take = (dm > nbd) || (dm == nbd && pid[k] < nbi);
        nbd = take ? dm : nbd;
        nbi = take ? pid[k] : nbi;
        nx = take ? px[k] : nx;
        ny = take ? py[k] : ny;
        nz = take ? pz[k] : nz;
      }
      bd = nbd; bi = nbi; bx = nx; by = ny; bz = nz;
    }
    unsigned long long dirty = __ballot(!skip);
    if (dirty != 0ull) {  // wave-uniform
      float rd = bd, rx = bx, ry = by, rz = bz;
      int ri = bi;
#pragma unroll
      for (int off = 32; off > 0; off >>= 1) {
        float od = __shfl_xor(rd, off);
        int oi = __shfl_xor(ri, off);
        float ox = __shfl_xor(rx, off);
        float oy = __shfl_xor(ry, off);
        float oz = __shfl_xor(rz, off);
        bool tk = (od > rd) || (od == rd && oi < ri);
        rd = tk ? od : rd; ri = tk ? oi : ri;
        rx = tk ? ox : rx; ry = tk ? oy : ry; rz = tk ? oz : rz;
      }
      if (lane == 0) {
        slotD[w] = rd; slotI[w] = ri;
        slotX[w] = rx; slotY[w] = ry; slotZ[w] = rz;
      }
    }
    __syncthreads();
    if (t < 16) {
      float rd = slotD[t], rx = slotX[t], ry = slotY[t], rz = slotZ[t];
      int ri = slotI[t];
#pragma unroll
      for (int off = 8; off > 0; off >>= 1) {
        float od = __shfl_xor(rd, off);
        int oi = __shfl_xor(ri, off);
        float ox = __shfl_xor(rx, off);
        float oy = __shfl_xor(ry, off);
        float oz = __shfl_xor(rz, off);
        bool tk = (od > rd) || (od == rd && oi < ri);
        rd = tk ? od : rd; ri = tk ? oi : ri;
        rx = tk ? ox : rx; ry = tk ? oy : ry; rz = tk ? oz : rz;
      }
      if (t == 0) {
        fXYZ[0] = rx; fXYZ[1] = ry; fXYZ[2] = rz;
        new_xyz[((size_t)b * M_ + it) * 3 + 0] = rx;
        new_xyz[((size_t)b * M_ + it) * 3 + 1] = ry;
        new_xyz[((size_t)b * M_ + it) * 3 + 2] = rz;
      }
    }
    __syncthreads();
    lx = fXYZ[0]; ly = fXYZ[1]; lz = fXYZ[2];
  }
}

// ---------------------------------------------------------------------------
// 2) Fused ball-query + grouping + MLP(67->128 relu ->256) + max over K.
//    One block (256 thr) per centroid. Ball query: wave w scans index chunk
//    [w*2048,(w+1)*2048) in order, ballot-appends first <=32 valid to its own
//    LDS list; lists concat in wave order == global index order (pointnet2
//    first-K semantics). Writes pre-BN pooled features TRANSPOSED into the
//    final (B,C2,M) output region (no scratch needed).
// ---------------------------------------------------------------------------
__global__ __launch_bounds__(256) void mlp_kernel(const float* __restrict__ xyz,
                                                  const float* __restrict__ x,
                                                  const float* __restrict__ W1,
                                                  const float* __restrict__ b1,
                                                  const float* __restrict__ W2,
                                                  const float* __restrict__ b2,
                                                  const float* __restrict__ new_xyz,
                                                  float* __restrict__ outp) {
  __shared__ float sGRed[32 * 69];   // group tile; unioned w/ 8x256 max-red
  __shared__ float sU[128 * 69];     // W1 staged; unioned w/ 32x256 W2 tile
  __shared__ float sH1[32 * 132];
  __shared__ int sWIdx[4][K_];
  __shared__ int sWCnt[4];
  __shared__ int sIdx[K_];
  __shared__ float sQ[3];

  const int gm = blockIdx.x;
  const int b = gm >> 11;    // M_ = 2048
  const int m = gm & 2047;
  const int t = threadIdx.x;
  const int lane = t & 63;
  const int w = t >> 6;
  const float* xb = xyz + (size_t)b * N_ * 3;

  if (t < 3) sQ[t] = new_xyz[(size_t)gm * 3 + t];
  __syncthreads();
  const float qx = sQ[0], qy = sQ[1], qz = sQ[2];
  // (float)(0.1*0.1) = 0x3C23D70A; 0.1f*0.1f rounds differently — wrong.
  const float R2 = (float)(0.1 * 0.1);

  // ---- ball query ----
  {
    int cnt = 0;
    const int cbeg = w * 2048, cend = cbeg + 2048;
    for (int base = cbeg; base < cend; base += 64) {
      int p = base + lane;
      float d2 = sqdist_rn(qx, qy, qz, xb[p * 3 + 0], xb[p * 3 + 1], xb[p * 3 + 2]);
      bool valid = d2 < R2;
      unsigned long long mask = __ballot(valid);
      if (valid) {
        int pos = cnt + __popcll(mask & ((1ull << lane) - 1ull));
        if (pos < K_) sWIdx[w][pos] = p;
      }
      cnt += __popcll(mask);
      if (cnt >= K_) break;  // wave-uniform
    }
    if (lane == 0) sWCnt[w] = (cnt < K_) ? cnt : K_;
  }
  __syncthreads();
  if (t < K_) {
    int c0 = sWCnt[0], c1 = sWCnt[1], c2 = sWCnt[2], c3 = sWCnt[3];
    int s1 = c0 + c1, s2 = s1 + c2, s3 = s2 + c3;
    int j = t, idx;
    if (j < c0) idx = sWIdx[0][j];
    else if (j < s1) idx = sWIdx[1][j - c0];
    else if (j < s2) idx = sWIdx[2][j - s1];
    else if (j < s3) idx = sWIdx[3][j - s2];
    else {
      int fw = c0 ? 0 : (c1 ? 1 : (c2 ? 2 : 3));
      idx = (s3 > 0) ? sWIdx[fw][0] : 0;  // fill with first valid index
    }
    sIdx[j] = idx;
  }
  __syncthreads();

  // ---- grouping: rel coords + features into sGRed (32 x 69 padded) ----
  if (t < K_) {
    int id = sIdx[t];
    sGRed[t * 69 + 0] = xb[id * 3 + 0] - qx;
    sGRed[t * 69 + 1] = xb[id * 3 + 1] - qy;
    sGRed[t * 69 + 2] = xb[id * 3 + 2] - qz;
  }
  {
    int r = t & 31;
    int c0 = (t >> 5) * 8;
    int id = sIdx[r];
    const float* xf = x + ((size_t)b * C0_ + c0) * N_ + id;
#pragma unroll
    for (int j = 0; j < 8; ++j) sGRed[r * 69 + 3 + c0 + j] = xf[(size_t)j * N_];
  }
  for (int i = t; i < C1_ * CIN_; i += 256) {
    sU[(i / CIN_) * 69 + (i % CIN_)] = W1[i];
  }
  __syncthreads();

  const int ol = t & 31;  // output-lane: o = ol + 32*j
  const int rg = t >> 5;  // row group: rows rg*4 .. rg*4+3

  // ---- layer 1: h1 = relu(G @ W1^T + b1), 4 rows x 4 outs per thread ----
  float acc[4][4] = {{0.f}};
  for (int c = 0; c < CIN_; ++c) {
    float g[4], wv[4];
#pragma unroll
    for (int i = 0; i < 4; ++i) g[i] = sGRed[(rg * 4 + i) * 69 + c];
#pragma unroll
    for (int j = 0; j < 4; ++j) wv[j] = sU[(ol + 32 * j) * 69 + c];
#pragma unroll
    for (int i = 0; i < 4; ++i)
#pragma unroll
      for (int j = 0; j < 4; ++j) acc[i][j] += g[i] * wv[j];
  }
#pragma unroll
  for (int j = 0; j < 4; ++j) {
    float bias = b1[ol + 32 * j];
#pragma unroll
    for (int i = 0; i < 4; ++i) {
      float v = acc[i][j] + bias;
      sH1[(rg * 4 + i) * 132 + ol + 32 * j] = fmaxf(v, 0.0f);
    }
  }

  // ---- layer 2: h2 = h1 @ W2^T, 4 rows x 8 outs per thread ----
  float acc2[4][8] = {{0.f}};
  for (int ct = 0; ct < 4; ++ct) {
    __syncthreads();  // sU reuse safe; (ct==0) also covers sH1 writes
    const float4* w4 = (const float4*)(W2 + (size_t)t * C1_ + ct * 32);
#pragma unroll
    for (int jj = 0; jj < 8; ++jj) {
      float4 v = w4[jj];
      sU[(jj * 4 + 0) * 256 + t] = v.x;
      sU[(jj * 4 + 1) * 256 + t] = v.y;
      sU[(jj * 4 + 2) * 256 + t] = v.z;
      sU[(jj * 4 + 3) * 256 + t] = v.w;
    }
    __syncthreads();
    for (int cc = 0; cc < 32; ++cc) {
      float h[4], wv[8];
#pragma unroll
      for (int i = 0; i < 4; ++i) h[i] = sH1[(rg * 4 + i) * 132 + ct * 32 + cc];
#pragma unroll
      for (int j = 0; j < 8; ++j) wv[j] = sU[cc * 256 + ol + 32 * j];
#pragma unroll
      for (int i = 0; i < 4; ++i)
#pragma unroll
        for (int j = 0; j < 8; ++j) acc2[i][j] += h[i] * wv[j];
    }
  }

  // ---- max over K, + b2 (max(x)+c == max(x+c): RN is monotone) ----
  __syncthreads();  // group tile dead; reuse sGRed as reduction buffer
#pragma unroll
  for (int j = 0; j < 8; ++j) {
    float pm = acc2[0][j];
#pragma unroll
    for (int i = 1; i < 4; ++i) pm = fmaxf(pm, acc2[i][j]);
    sGRed[rg * 256 + ol + 32 * j] = pm;
  }
  __syncthreads();
  {
    int o = t;
    float v = sGRed[o];
#pragma unroll
    for (int g = 1; g < 8; ++g) v = fmaxf(v, sGRed[g * 256 + o]);
    v += b2[o];
    // transposed store into final (B, C2, M) layout (pre-BN)
    outp[((size_t)(b * C2_ + o)) * M_ + m] = v;
  }
}

// ---------------------------------------------------------------------------
// 3) BN stats per channel (deterministic, double accum). One block / channel.
// ---------------------------------------------------------------------------
__global__ __launch_bounds__(256) void bn_stats_kernel(const float* __restrict__ outp,
                                                       const float* __restrict__ gamma,
                                                       float* __restrict__ stats) {
  const int o = blockIdx.x;
  const int t = threadIdx.x;
  double s = 0.0, s2 = 0.0;
  for (int b = 0; b < B_; ++b) {
    const float* p = outp + ((size_t)(b * C2_ + o)) * M_;
    for (int i = t; i < M_; i += 256) {
      float v = p[i];
      s += (double)v;
      s2 += (double)v * (double)v;
    }
  }
#pragma unroll
  for (int off = 32; off > 0; off >>= 1) {
    s += __shfl_xor(s, off);
    s2 += __shfl_xor(s2, off);
  }
  __shared__ double aS[4], aS2[4];
  if ((t & 63) == 0) { aS[t >> 6] = s; aS2[t >> 6] = s2; }
  __syncthreads();
  if (t == 0) {
    double S = aS[0] + aS[1] + aS[2] + aS[3];
    double S2 = aS2[0] + aS2[1] + aS2[2] + aS2[3];
    double mean = S / (double)(B_ * M_);
    double var = S2 / (double)(B_ * M_) - mean * mean;
    float rstd = 1.0f / sqrtf((float)var + 1e-5f);
    stats[o] = (float)mean;
    stats[C2_ + o] = gamma[o] * rstd;
  }
}

// ---------------------------------------------------------------------------
// 4) BN apply, in place on the (B,C2,M) output region. float4-vectorized.
// ---------------------------------------------------------------------------
__global__ __launch_bounds__(256) void bn_apply_kernel(float* __restrict__ outp,
                                                       const float* __restrict__ stats,
                                                       const float* __restrict__ beta) {
  const int i4 = blockIdx.x * 256 + threadIdx.x;  // B_*C2_*M_/4 = 262144
  const int ch = (i4 >> 9) & 255;                 // M_/4 = 512 float4 / chan
  const float mean = stats[ch];
  const float scale = stats[C2_ + ch];
  const float bt = beta[ch];
  float4 v = ((const float4*)outp)[i4];
  v.x = (v.x - mean) * scale + bt;
  v.y = (v.y - mean) * scale + bt;
  v.z = (v.z - mean) * scale + bt;
  v.w = (v.w - mean) * scale + bt;
  ((float4*)outp)[i4] = v;
}

// ---------------------------------------------------------------------------
extern "C" void kernel_launch(void* const* d_in, const int* in_sizes, int n_in,
                              void* d_out, int out_size, void* d_ws, size_t ws_size,
                              hipStream_t stream) {
  const float* xyz   = (const float*)d_in[0];
  const float* x     = (const float*)d_in[1];
  const float* W1    = (const float*)d_in[2];
  const float* b1    = (const float*)d_in[3];
  const float* W2    = (const float*)d_in[4];
  const float* b2    = (const float*)d_in[5];
  const float* gamma = (const float*)d_in[6];
  const float* beta  = (const float*)d_in[7];

  float* new_xyz = (float*)d_out;                       // (B, M, 3)
  float* outp    = (float*)d_out + (size_t)B_ * M_ * 3; // (B, C2, M)
  float* stats   = (float*)d_ws;                        // 2*C2 floats = 2 KB

  fps_kernel<<<B_, 1024, 0, stream>>>(xyz, new_xyz);
  mlp_kernel<<<B_ * M_, 256, 0, stream>>>(xyz, x, W1, b1, W2, b2, new_xyz, outp);
  bn_stats_kernel<<<C2_, 256, 0, stream>>>(outp, gamma, stats);
  bn_apply_kernel<<<(B_ * C2_ * M_ / 4) / 256, 256, 0, stream>>>(outp, stats, beta);
}

// Round 4
// 3320.028 us; speedup vs baseline: 1.4154x; 1.4154x over previous
//
#include <hip/hip_runtime.h>
#include <cstdint>
#include <cstddef>

#define B_   2
#define N_   8192
#define M_   2048
#define K_   32
#define C0_  64
#define C1_  128
#define C2_  256
#define CIN_ 67

// Exact-match distance: reference computes sum((a-b)**2, axis=-1) in f32 as
// ((dx^2 + dy^2) + dz^2) with no FMA contraction. _rn intrinsics forbid
// contract-fast fma fusion (would flip argmax / radius-boundary decisions).
__device__ __forceinline__ float sqdist_rn(float ax, float ay, float az,
                                           float bx, float by, float bz) {
  float dx = __fsub_rn(ax, bx);
  float dy = __fsub_rn(ay, by);
  float dz = __fsub_rn(az, bz);
  return __fadd_rn(__fadd_rn(__fmul_rn(dx, dx), __fmul_rn(dy, dy)),
                   __fmul_rn(dz, dz));
}

__device__ __forceinline__ int morton8(int ix, int iy, int iz) {
  int m = 0;
#pragma unroll
  for (int b = 0; b < 3; ++b) {
    m |= (((ix >> b) & 1) << (3 * b + 2)) | (((iy >> b) & 1) << (3 * b + 1)) |
         (((iz >> b) & 1) << (3 * b + 0));
  }
  return m;
}

// Wave-64 max of a non-negative float via DPP (VALU-latency cross-lane):
// classic gfx9 sequence row_shr 1/2/4/8 then row_bcast15/31; result lane 63.
// bound_ctrl=false + old=self => invalid lanes contribute max(v,v)=v.
__device__ __forceinline__ float wave_max_f32_dpp(float v) {
  int x = __float_as_int(v);
#define FPS_STEP(ctrl)                                                      \
  {                                                                         \
    int y = __builtin_amdgcn_update_dpp(x, x, ctrl, 0xf, 0xf, false);       \
    x = __float_as_int(fmaxf(__int_as_float(x), __int_as_float(y)));        \
  }
  FPS_STEP(0x111)  // row_shr:1
  FPS_STEP(0x112)  // row_shr:2
  FPS_STEP(0x114)  // row_shr:4
  FPS_STEP(0x118)  // row_shr:8
  FPS_STEP(0x142)  // row_bcast:15
  FPS_STEP(0x143)  // row_bcast:31
#undef FPS_STEP
  return __int_as_float(__builtin_amdgcn_readlane(x, 63));
}

// ---------------------------------------------------------------------------
// 1) Furthest point sampling, exact spatial pruning + DPP reductions.
//    One block (1024 thr, 16 waves) per batch.
//    Setup: counting-sort by 8^3 Morton cell into LDS; thread t owns sorted
//    points [8t,8t+8) in registers + bounding sphere (c,r). Scatter order is
//    atomic-nondeterministic but output-invariant (exact min updates; skips
//    provably no-op; argmax ties break on ORIGINAL index payload).
//    Per iteration (2 barriers, zero global traffic):
//      (1) all: read prev winner coords from LDS snew; conservative sphere
//          skip test; dirty threads redo exact 8-pt update + candidate
//          (bd = max d, tie->min pid, carry sorted pos). Dirty WAVES reduce
//          via DPP f32-max + ballot tie-path and lane0 writes a packed
//          u64 key (d_bits<<32 | ~pid) + pos slot. Clean waves keep cached
//          slots (valid: their max is unchanged; winner's wave is always
//          dirty since its d becomes 0).
//      (2) barrier A; wave 0 reduces 16 slots with 4-step row-16 DPP u64
//          max, looks up winner coords sx/sy/sz[pos], writes snew[it*3..];
//          barrier B.
//    After the loop: dump snew to new_xyz coalesced.
//    Tie-break everywhere == jnp.argmax first-occurrence.
// ---------------------------------------------------------------------------
__global__ __launch_bounds__(1024, 1) void fps_kernel(const float* __restrict__ xyz,
                                                      float* __restrict__ new_xyz) {
  const int b = blockIdx.x;
  const int t = threadIdx.x;
  const int lane = t & 63;
  const int w = t >> 6;
  const float* xb = xyz + (size_t)b * N_ * 3;

  __shared__ float sx[N_], sy[N_], sz[N_];
  __shared__ int sid[N_];
  __shared__ int hist[512];
  __shared__ int boff[512];
  __shared__ int wsum[8];
  __shared__ unsigned long long sKey[16];
  __shared__ int sPos[16];
  __shared__ float snew[M_ * 3];  // selected coords ring (dumped at end)

  // ---- counting sort by morton cell ----
  if (t < 512) hist[t] = 0;
  __syncthreads();
#pragma unroll
  for (int rr = 0; rr < 8; ++rr) {
    int i = rr * 1024 + t;
    float X = xb[i * 3 + 0], Y = xb[i * 3 + 1], Z = xb[i * 3 + 2];
    int ix = min(7, max(0, (int)(X * 8.0f)));
    int iy = min(7, max(0, (int)(Y * 8.0f)));
    int iz = min(7, max(0, (int)(Z * 8.0f)));
    atomicAdd(&hist[morton8(ix, iy, iz)], 1);
  }
  __syncthreads();
  // exclusive scan of 512 bins (8 active waves)
  {
    int ov = (t < 512) ? hist[t] : 0;
    int v = ov;
#pragma unroll
    for (int off = 1; off < 64; off <<= 1) {
      int n = __shfl_up(v, off);
      if (lane >= off) v += n;
    }
    if (t < 512 && lane == 63) wsum[w] = v;
    __syncthreads();
    if (t == 0) {
      int acc = 0;
#pragma unroll
      for (int j = 0; j < 8; ++j) { int x0 = wsum[j]; wsum[j] = acc; acc += x0; }
    }
    __syncthreads();
    if (t < 512) boff[t] = v - ov + wsum[w];
  }
  __syncthreads();
#pragma unroll
  for (int rr = 0; rr < 8; ++rr) {
    int i = rr * 1024 + t;
    float X = xb[i * 3 + 0], Y = xb[i * 3 + 1], Z = xb[i * 3 + 2];
    int ix = min(7, max(0, (int)(X * 8.0f)));
    int iy = min(7, max(0, (int)(Y * 8.0f)));
    int iz = min(7, max(0, (int)(Z * 8.0f)));
    int pos = atomicAdd(&boff[morton8(ix, iy, iz)], 1);
    sx[pos] = X; sy[pos] = Y; sz[pos] = Z; sid[pos] = i;
  }

  // ---- per-thread bucket: 8 points into registers + bounding sphere ----
  if (t == 0) {
    snew[0] = xb[0]; snew[1] = xb[1]; snew[2] = xb[2];  // first index = 0
  }
  __syncthreads();

  float px[8], py[8], pz[8], d[8];
  int pid[8];
#pragma unroll
  for (int k = 0; k < 8; ++k) {
    int p = 8 * t + k;
    px[k] = sx[p]; py[k] = sy[p]; pz[k] = sz[p]; pid[k] = sid[p];
    d[k] = 1e10f;  // == f32(10000000000.0), matches jnp init exactly
  }
  float cx = 0.f, cy = 0.f, cz = 0.f;
#pragma unroll
  for (int k = 0; k < 8; ++k) { cx += px[k]; cy += py[k]; cz += pz[k]; }
  cx *= 0.125f; cy *= 0.125f; cz *= 0.125f;
  float r2m = 0.f;
#pragma unroll
  for (int k = 0; k < 8; ++k) {
    float dx = px[k] - cx, dy = py[k] - cy, dz = pz[k] - cz;
    r2m = fmaxf(r2m, dx * dx + dy * dy + dz * dz);
  }
  const float rad = sqrtf(r2m) * 1.00002f + 1e-12f;

  // cached per-thread candidate; bd=1e10 guarantees iter 1 never skips,
  // so every slot is written before first read.
  float bd = 1e10f;
  int bpid = pid[0], bpos = 8 * t;

  for (int it = 1; it < M_; ++it) {
    const float lx = snew[(it - 1) * 3 + 0];
    const float ly = snew[(it - 1) * 3 + 1];
    const float lz = snew[(it - 1) * 3 + 2];

    // ---- conservative skip test (pruning-quality precision only) ----
    float ex = lx - cx, ey = ly - cy, ez = lz - cz;
    float dc2 = ex * ex + ey * ey + ez * ez;
    float s = sqrtf(dc2) - rad;
    bool skip = (s > 0.f) && (s * s > bd * 1.0001f);
    if (!skip) {
      float nbd = -1.f; int nbi = 0, nbp = 0;
#pragma unroll
      for (int k = 0; k < 8; ++k) {
        float dist = sqdist_rn(px[k], py[k], pz[k], lx, ly, lz);
        float dm = fminf(d[k], dist);
        d[k] = dm;
        bool take = (dm > nbd) || (dm == nbd && pid[k] < nbi);
        nbd = take ? dm : nbd;
        nbi = take ? pid[k] : nbi;
        nbp = take ? (8 * t + k) : nbp;
      }
      bd = nbd; bpid = nbi; bpos = nbp;
    }
    unsigned long long dirty = __ballot(!skip);
    if (dirty != 0ull) {  // wave-uniform: this wave's slot must refresh
      float wmax = wave_max_f32_dpp(bd);
      unsigned long long tied = __ballot(bd == wmax);
      // min ORIGINAL pid among tied lanes (usually 1 iteration)
      int bestpid = 0x7FFFFFFF, wl = 0;
      while (tied) {
        int l = __ffsll(tied) - 1;
        tied &= tied - 1;
        int p = __builtin_amdgcn_readlane(bpid, l);
        if (p < bestpid) { bestpid = p; wl = l; }
      }
      int wpos = __builtin_amdgcn_readlane(bpos, wl);
      if (lane == 0) {
        sKey[w] = ((unsigned long long)(unsigned)__float_as_int(wmax) << 32) |
                  (unsigned)(0xFFFFFFFFu - (unsigned)bestpid);
        sPos[w] = wpos;
      }
    }
    __syncthreads();  // A: slot writes visible
    if (w == 0) {
      int sl = lane & 15;  // rows replicate the 16 slots -> row DPP works
      unsigned long long key = sKey[sl];
      int pos = sPos[sl];
#define FPS_STEP2(ctrl)                                                        \
      {                                                                        \
        int klo = (int)(unsigned)key, khi = (int)(unsigned)(key >> 32);        \
        int olo = __builtin_amdgcn_update_dpp(klo, klo, ctrl, 0xf, 0xf, false);\
        int ohi = __builtin_amdgcn_update_dpp(khi, khi, ctrl, 0xf, 0xf, false);\
        int ops = __builtin_amdgcn_update_dpp(pos, pos, ctrl, 0xf, 0xf, false);\
        unsigned long long okey =                                              \
            ((unsigned long long)(unsigned)ohi << 32) | (unsigned)olo;         \
        if (okey > key) { key = okey; pos = ops; }                             \
      }
      FPS_STEP2(0x111)  // row_shr:1
      FPS_STEP2(0x112)  // row_shr:2
      FPS_STEP2(0x114)  // row_shr:4
      FPS_STEP2(0x118)  // row_shr:8
#undef FPS_STEP2
      int winPos = __builtin_amdgcn_readlane(pos, 15);  // uniform
      float wx = sx[winPos], wy = sy[winPos], wz = sz[winPos];  // broadcast
      if (lane == 0) {
        snew[it * 3 + 0] = wx;
        snew[it * 3 + 1] = wy;
        snew[it * 3 + 2] = wz;
      }
    }
    __syncthreads();  // B: snew[it] visible; slots stable for next writes
  }

  // ---- coalesced dump of selected coords ----
  for (int i = t; i < M_ * 3; i += 1024) {
    new_xyz[(size_t)b * M_ * 3 + i] = snew[i];
  }
}

// ---------------------------------------------------------------------------
// 2) Fused ball-query + grouping + MLP(67->128 relu ->256) + max over K.
//    One block (256 thr) per centroid. Ball query: wave w scans index chunk
//    [w*2048,(w+1)*2048) in order, ballot-appends first <=32 valid to its own
//    LDS list; lists concat in wave order == global index order (pointnet2
//    first-K semantics). Writes pre-BN pooled features TRANSPOSED into the
//    final (B,C2,M) output region (no scratch needed).
// ---------------------------------------------------------------------------
__global__ __launch_bounds__(256) void mlp_kernel(const float* __restrict__ xyz,
                                                  const float* __restrict__ x,
                                                  const float* __restrict__ W1,
                                                  const float* __restrict__ b1,
                                                  const float* __restrict__ W2,
                                                  const float* __restrict__ b2,
                                                  const float* __restrict__ new_xyz,
                                                  float* __restrict__ outp) {
  __shared__ float sGRed[32 * 69];   // group tile; unioned w/ 8x256 max-red
  __shared__ float sU[128 * 69];     // W1 staged; unioned w/ 32x256 W2 tile
  __shared__ float sH1[32 * 132];
  __shared__ int sWIdx[4][K_];
  __shared__ int sWCnt[4];
  __shared__ int sIdx[K_];
  __shared__ float sQ[3];

  const int gm = blockIdx.x;
  const int b = gm >> 11;    // M_ = 2048
  const int m = gm & 2047;
  const int t = threadIdx.x;
  const int lane = t & 63;
  const int w = t >> 6;
  const float* xb = xyz + (size_t)b * N_ * 3;

  if (t < 3) sQ[t] = new_xyz[(size_t)gm * 3 + t];
  __syncthreads();
  const float qx = sQ[0], qy = sQ[1], qz = sQ[2];
  // (float)(0.1*0.1) = 0x3C23D70A; 0.1f*0.1f rounds differently — wrong.
  const float R2 = (float)(0.1 * 0.1);

  // ---- ball query ----
  {
    int cnt = 0;
    const int cbeg = w * 2048, cend = cbeg + 2048;
    for (int base = cbeg; base < cend; base += 64) {
      int p = base + lane;
      float d2 = sqdist_rn(qx, qy, qz, xb[p * 3 + 0], xb[p * 3 + 1], xb[p * 3 + 2]);
      bool valid = d2 < R2;
      unsigned long long mask = __ballot(valid);
      if (valid) {
        int pos = cnt + __popcll(mask & ((1ull << lane) - 1ull));
        if (pos < K_) sWIdx[w][pos] = p;
      }
      cnt += __popcll(mask);
      if (cnt >= K_) break;  // wave-uniform
    }
    if (lane == 0) sWCnt[w] = (cnt < K_) ? cnt : K_;
  }
  __syncthreads();
  if (t < K_) {
    int c0 = sWCnt[0], c1 = sWCnt[1], c2 = sWCnt[2], c3 = sWCnt[3];
    int s1 = c0 + c1, s2 = s1 + c2, s3 = s2 + c3;
    int j = t, idx;
    if (j < c0) idx = sWIdx[0][j];
    else if (j < s1) idx = sWIdx[1][j - c0];
    else if (j < s2) idx = sWIdx[2][j - s1];
    else if (j < s3) idx = sWIdx[3][j - s2];
    else {
      int fw = c0 ? 0 : (c1 ? 1 : (c2 ? 2 : 3));
      idx = (s3 > 0) ? sWIdx[fw][0] : 0;  // fill with first valid index
    }
    sIdx[j] = idx;
  }
  __syncthreads();

  // ---- grouping: rel coords + features into sGRed (32 x 69 padded) ----
  if (t < K_) {
    int id = sIdx[t];
    sGRed[t * 69 + 0] = xb[id * 3 + 0] - qx;
    sGRed[t * 69 + 1] = xb[id * 3 + 1] - qy;
    sGRed[t * 69 + 2] = xb[id * 3 + 2] - qz;
  }
  {
    int r = t & 31;
    int c0 = (t >> 5) * 8;
    int id = sIdx[r];
    const float* xf = x + ((size_t)b * C0_ + c0) * N_ + id;
#pragma unroll
    for (int j = 0; j < 8; ++j) sGRed[r * 69 + 3 + c0 + j] = xf[(size_t)j * N_];
  }
  for (int i = t; i < C1_ * CIN_; i += 256) {
    sU[(i / CIN_) * 69 + (i % CIN_)] = W1[i];
  }
  __syncthreads();

  const int ol = t & 31;  // output-lane: o = ol + 32*j
  const int rg = t >> 5;  // row group: rows rg*4 .. rg*4+3

  // ---- layer 1: h1 = relu(G @ W1^T + b1), 4 rows x 4 outs per thread ----
  float acc[4][4] = {{0.f}};
  for (int c = 0; c < CIN_; ++c) {
    float g[4], wv[4];
#pragma unroll
    for (int i = 0; i < 4; ++i) g[i] = sGRed[(rg * 4 + i) * 69 + c];
#pragma unroll
    for (int j = 0; j < 4; ++j) wv[j] = sU[(ol + 32 * j) * 69 + c];
#pragma unroll
    for (int i = 0; i < 4; ++i)
#pragma unroll
      for (int j = 0; j < 4; ++j) acc[i][j] += g[i] * wv[j];
  }
#pragma unroll
  for (int j = 0; j < 4; ++j) {
    float bias = b1[ol + 32 * j];
#pragma unroll
    for (int i = 0; i < 4; ++i) {
      float v = acc[i][j] + bias;
      sH1[(rg * 4 + i) * 132 + ol + 32 * j] = fmaxf(v, 0.0f);
    }
  }

  // ---- layer 2: h2 = h1 @ W2^T, 4 rows x 8 outs per thread ----
  float acc2[4][8] = {{0.f}};
  for (int ct = 0; ct < 4; ++ct) {
    __syncthreads();  // sU reuse safe; (ct==0) also covers sH1 writes
    const float4* w4 = (const float4*)(W2 + (size_t)t * C1_ + ct * 32);
#pragma unroll
    for (int jj = 0; jj < 8; ++jj) {
      float4 v = w4[jj];
      sU[(jj * 4 + 0) * 256 + t] = v.x;
      sU[(jj * 4 + 1) * 256 + t] = v.y;
      sU[(jj * 4 + 2) * 256 + t] = v.z;
      sU[(jj * 4 + 3) * 256 + t] = v.w;
    }
    __syncthreads();
    for (int cc = 0; cc < 32; ++cc) {
      float h[4], wv[8];
#pragma unroll
      for (int i = 0; i < 4; ++i) h[i] = sH1[(rg * 4 + i) * 132 + ct * 32 + cc];
#pragma unroll
      for (int j = 0; j < 8; ++j) wv[j] = sU[cc * 256 + ol + 32 * j];
#pragma unroll
      for (int i = 0; i < 4; ++i)
#pragma unroll
        for (int j = 0; j < 8; ++j) acc2[i][j] += h[i] * wv[j];
    }
  }

  // ---- max over K, + b2 (max(x)+c == max(x+c): RN is monotone) ----
  __syncthreads();  // group tile dead; reuse sGRed as reduction buffer
#pragma unroll
  for (int j = 0; j < 8; ++j) {
    float pm = acc2[0][j];
#pragma unroll
    for (int i = 1; i < 4; ++i) pm = fmaxf(pm, acc2[i][j]);
    sGRed[rg * 256 + ol + 32 * j] = pm;
  }
  __syncthreads();
  {
    int o = t;
    float v = sGRed[o];
#pragma unroll
    for (int g = 1; g < 8; ++g) v = fmaxf(v, sGRed[g * 256 + o]);
    v += b2[o];
    // transposed store into final (B, C2, M) layout (pre-BN)
    outp[((size_t)(b * C2_ + o)) * M_ + m] = v;
  }
}

// ---------------------------------------------------------------------------
// 3) BN stats per channel (deterministic, double accum). One block / channel.
// ---------------------------------------------------------------------------
__global__ __launch_bounds__(256) void bn_stats_kernel(const float* __restrict__ outp,
                                                       const float* __restrict__ gamma,
                                                       float* __restrict__ stats) {
  const int o = blockIdx.x;
  const int t = threadIdx.x;
  double s = 0.0, s2 = 0.0;
  for (int b = 0; b < B_; ++b) {
    const float* p = outp + ((size_t)(b * C2_ + o)) * M_;
    for (int i = t; i < M_; i += 256) {
      float v = p[i];
      s += (double)v;
      s2 += (double)v * (double)v;
    }
  }
#pragma unroll
  for (int off = 32; off > 0; off >>= 1) {
    s += __shfl_xor(s, off);
    s2 += __shfl_xor(s2, off);
  }
  __shared__ double aS[4], aS2[4];
  if ((t & 63) == 0) { aS[t >> 6] = s; aS2[t >> 6] = s2; }
  __syncthreads();
  if (t == 0) {
    double S = aS[0] + aS[1] + aS[2] + aS[3];
    double S2 = aS2[0] + aS2[1] + aS2[2] + aS2[3];
    double mean = S / (double)(B_ * M_);
    double var = S2 / (double)(B_ * M_) - mean * mean;
    float rstd = 1.0f / sqrtf((float)var + 1e-5f);
    stats[o] = (float)mean;
    stats[C2_ + o] = gamma[o] * rstd;
  }
}

// ---------------------------------------------------------------------------
// 4) BN apply, in place on the (B,C2,M) output region. float4-vectorized.
// ---------------------------------------------------------------------------
__global__ __launch_bounds__(256) void bn_apply_kernel(float* __restrict__ outp,
                                                       const float* __restrict__ stats,
                                                       const float* __restrict__ beta) {
  const int i4 = blockIdx.x * 256 + threadIdx.x;  // B_*C2_*M_/4 = 262144
  const int ch = (i4 >> 9) & 255;                 // M_/4 = 512 float4 / chan
  const float mean = stats[ch];
  const float scale = stats[C2_ + ch];
  const float bt = beta[ch];
  float4 v = ((const float4*)outp)[i4];
  v.x = (v.x - mean) * scale + bt;
  v.y = (v.y - mean) * scale + bt;
  v.z = (v.z - mean) * scale + bt;
  v.w = (v.w - mean) * scale + bt;
  ((float4*)outp)[i4] = v;
}

// ---------------------------------------------------------------------------
extern "C" void kernel_launch(void* const* d_in, const int* in_sizes, int n_in,
                              void* d_out, int out_size, void* d_ws, size_t ws_size,
                              hipStream_t stream) {
  const float* xyz   = (const float*)d_in[0];
  const float* x     = (const float*)d_in[1];
  const float* W1    = (const float*)d_in[2];
  const float* b1    = (const float*)d_in[3];
  const float* W2    = (const float*)d_in[4];
  const float* b2    = (const float*)d_in[5];
  const float* gamma = (const float*)d_in[6];
  const float* beta  = (const float*)d_in[7];

  float* new_xyz = (float*)d_out;                       // (B, M, 3)
  float* outp    = (float*)d_out + (size_t)B_ * M_ * 3; // (B, C2, M)
  float* stats   = (float*)d_ws;                        // 2*C2 floats = 2 KB

  fps_kernel<<<B_, 1024, 0, stream>>>(xyz, new_xyz);
  mlp_kernel<<<B_ * M_, 256, 0, stream>>>(xyz, x, W1, b1, W2, b2, new_xyz, outp);
  bn_stats_kernel<<<C2_, 256, 0, stream>>>(outp, gamma, stats);
  bn_apply_kernel<<<(B_ * C2_ * M_ / 4) / 256, 256, 0, stream>>>(outp, stats, beta);
}